// Round 1
// baseline (1362.347 us; speedup 1.0000x reference)
//
#include <hip/hip_runtime.h>
#include <math.h>

#define HWN 9216   // 96*96
#define HD 96
#define WD 96
#define CD 128
#define BD 4

// ---------------- transpose w_def[o][c][k] -> wt[k][o][c] ----------------
__global__ __launch_bounds__(256) void transpose_wdef_kernel(
    const float* __restrict__ wd, float* __restrict__ wt) {
  int i = blockIdx.x * 256 + threadIdx.x;
  if (i >= 9 * 128 * 128) return;
  int c = i & 127;
  int o = (i >> 7) & 127;
  int k = i >> 14;
  wt[i] = wd[o * 1152 + c * 9 + k];
}

// ---------------- per-(b,c) instance norm stats ----------------
__global__ __launch_bounds__(256) void stats_kernel(
    const float* __restrict__ src, float* __restrict__ stats) {
  int bc = blockIdx.x;  // b*C + c
  const float* p = src + (size_t)bc * HWN;
  float s = 0.f, s2 = 0.f;
  for (int i = threadIdx.x; i < HWN; i += 256) {
    float v = p[i];
    s += v;
    s2 += v * v;
  }
  for (int off = 32; off > 0; off >>= 1) {
    s += __shfl_down(s, off, 64);
    s2 += __shfl_down(s2, off, 64);
  }
  __shared__ float as[4], as2[4];
  int wid = threadIdx.x >> 6, lid = threadIdx.x & 63;
  if (lid == 0) { as[wid] = s; as2[wid] = s2; }
  __syncthreads();
  if (threadIdx.x == 0) {
    float S = 0.f, S2 = 0.f;
    for (int w = 0; w < 4; ++w) { S += as[w]; S2 += as2[w]; }
    float mu = S / (float)HWN;
    float var = S2 / (float)HWN - mu * mu;
    stats[bc * 2] = mu;
    stats[bc * 2 + 1] = rsqrtf(var + 1e-5f);
  }
}

// ---------------- normalize + LeakyReLU ----------------
__global__ __launch_bounds__(256) void norm_lrelu_kernel(
    const float* __restrict__ src, const float* __restrict__ stats,
    const float* __restrict__ gamma, const float* __restrict__ beta,
    float* __restrict__ dst) {
  int idx = blockIdx.x * 256 + threadIdx.x;  // total = 4*128*9216, exact grid
  int bc = idx / HWN;
  int c = bc & 127;
  float mu = stats[bc * 2], rs = stats[bc * 2 + 1];
  float v = (src[idx] - mu) * rs * gamma[c] + beta[c];
  dst[idx] = v >= 0.f ? v : 0.2f * v;
}

// ---------------- direct 3x3 conv, pad=1 ----------------
// grid: (9 spatial tiles of 32x32, ceil(CO/4), B); block 256
// each thread: 4 out-channels x 2x2 positions
__global__ __launch_bounds__(256) void conv3x3_kernel(
    const float* __restrict__ in, const float* __restrict__ w,
    const float* __restrict__ bias, float* __restrict__ out,
    int CI, int CO) {
  __shared__ float tile[34 * 34];
  __shared__ float wl[36];
  const int tgrid = 3;  // 96/32
  int tid = blockIdx.x;
  int ty0 = (tid / tgrid) * 32, tx0 = (tid % tgrid) * 32;
  int cog = blockIdx.y * 4;
  int b = blockIdx.z;
  int t = threadIdx.x;
  int lx = t & 15, ly = t >> 4;
  float acc[4][2][2] = {};
  const float* inb = in + (size_t)b * CI * HWN;
  for (int ci = 0; ci < CI; ++ci) {
    __syncthreads();
    const float* inc = inb + ci * HWN;
    for (int i = t; i < 34 * 34; i += 256) {
      int r = i / 34, cc = i % 34;
      int gy = ty0 - 1 + r, gx = tx0 - 1 + cc;
      float v = 0.f;
      if ((unsigned)gy < 96u && (unsigned)gx < 96u) v = inc[gy * WD + gx];
      tile[i] = v;
    }
    if (t < 36) {
      int j = t / 9, kk = t % 9;
      int co = cog + j;
      wl[t] = (co < CO) ? w[(size_t)co * CI * 9 + ci * 9 + kk] : 0.f;
    }
    __syncthreads();
    int Y = 2 * ly, X = 2 * lx;
    float inr[4][4];
#pragma unroll
    for (int r = 0; r < 4; ++r)
#pragma unroll
      for (int cc = 0; cc < 4; ++cc) inr[r][cc] = tile[(Y + r) * 34 + X + cc];
#pragma unroll
    for (int j = 0; j < 4; ++j) {
#pragma unroll
      for (int a = 0; a < 3; ++a)
#pragma unroll
        for (int bb = 0; bb < 3; ++bb) {
          float wv = wl[j * 9 + a * 3 + bb];
          acc[j][0][0] += inr[a][bb] * wv;
          acc[j][0][1] += inr[a][bb + 1] * wv;
          acc[j][1][0] += inr[a + 1][bb] * wv;
          acc[j][1][1] += inr[a + 1][bb + 1] * wv;
        }
    }
  }
  for (int j = 0; j < 4; ++j) {
    int co = cog + j;
    if (co >= CO) break;
    float bv = bias[co];
    for (int r = 0; r < 2; ++r)
      for (int cc = 0; cc < 2; ++cc) {
        int gy = ty0 + 2 * ly + r, gx = tx0 + 2 * lx + cc;
        out[(((size_t)b * CO + co) * HD + gy) * WD + gx] = acc[j][r][cc] + bv;
      }
  }
}

// ---------------- deformable conv + residual ----------------
// grid: (144 tiles of 8x8, B); block 256
__global__ __launch_bounds__(256) void deform_kernel(
    const float* __restrict__ h2, const float* __restrict__ om,
    const float* __restrict__ wt, const float* __restrict__ x,
    float* __restrict__ out) {
  __shared__ __align__(16) int offs[9][64][4];
  __shared__ __align__(16) float wgt[9][64][4];
  __shared__ __align__(16) float Sk[128][64];
  int b = blockIdx.y;
  int tileid = blockIdx.x;
  int Y0 = (tileid / 12) * 8, X0 = (tileid % 12) * 8;
  int t = threadIdx.x;
  const float* omb = om + (size_t)b * 27 * HWN;

  // phase 1: bilinear params per (k, p)
  for (int i = t; i < 576; i += 256) {
    int k = i >> 6, p = i & 63;
    int yy = Y0 + (p >> 3), xx = X0 + (p & 7);
    int pix = yy * WD + xx;
    float dy = omb[(2 * k) * HWN + pix];
    float dx = omb[(2 * k + 1) * HWN + pix];
    float mv = omb[(18 + k) * HWN + pix];
    float mask = 1.0f / (1.0f + expf(-mv));
    float py = dy + (float)(yy - 1 + (k / 3));
    float px = dx + (float)(xx - 1 + (k % 3));
    float fy = floorf(py), fx = floorf(px);
    float lyf = py - fy, lxf = px - fx;
    int y0 = (int)fy, x0 = (int)fx;
    int y1 = y0 + 1, x1 = x0 + 1;
    bool vy0 = (y0 >= 0) && (y0 < HD);
    bool vy1 = (y1 >= 0) && (y1 < HD);
    bool vx0 = (x0 >= 0) && (x0 < WD);
    bool vx1 = (x1 >= 0) && (x1 < WD);
    int y0c = min(max(y0, 0), HD - 1), y1c = min(max(y1, 0), HD - 1);
    int x0c = min(max(x0, 0), WD - 1), x1c = min(max(x1, 0), WD - 1);
    offs[k][p][0] = y0c * WD + x0c;
    offs[k][p][1] = y0c * WD + x1c;
    offs[k][p][2] = y1c * WD + x0c;
    offs[k][p][3] = y1c * WD + x1c;
    wgt[k][p][0] = (1.f - lyf) * (1.f - lxf) * ((vy0 && vx0) ? mask : 0.f);
    wgt[k][p][1] = (1.f - lyf) * lxf * ((vy0 && vx1) ? mask : 0.f);
    wgt[k][p][2] = lyf * (1.f - lxf) * ((vy1 && vx0) ? mask : 0.f);
    wgt[k][p][3] = lyf * lxf * ((vy1 && vx1) ? mask : 0.f);
  }
  __syncthreads();

  float acc[8][4] = {};
  int po = t & 15, og = t >> 4;
  int po4 = po * 4;
  const float* hb = h2 + (size_t)b * CD * HWN;

  for (int k = 0; k < 9; ++k) {
    if (k) __syncthreads();  // protect Sk from previous iteration's readers
    // phase 2: sample S[c][p] (mask folded in)
    {
      int p = t & 63;
      int cbase = (t >> 6) * 32;
      int o0 = offs[k][p][0], o1 = offs[k][p][1];
      int o2 = offs[k][p][2], o3 = offs[k][p][3];
      float w0 = wgt[k][p][0], w1v = wgt[k][p][1];
      float w2 = wgt[k][p][2], w3 = wgt[k][p][3];
      for (int s = 0; s < 32; ++s) {
        int c = cbase + s;
        const float* hc = hb + (size_t)c * HWN;
        Sk[c][p] = w0 * hc[o0] + w1v * hc[o1] + w2 * hc[o2] + w3 * hc[o3];
      }
    }
    __syncthreads();
    // phase 3: GEMM acc[o][p] += wt[k][o][c] * Sk[c][p]
    const float* wtk = wt + (size_t)k * 128 * 128;
#pragma unroll 4
    for (int c4 = 0; c4 < 128; c4 += 4) {
      float4 s0 = *(const float4*)&Sk[c4 + 0][po4];
      float4 s1 = *(const float4*)&Sk[c4 + 1][po4];
      float4 s2 = *(const float4*)&Sk[c4 + 2][po4];
      float4 s3 = *(const float4*)&Sk[c4 + 3][po4];
#pragma unroll
      for (int j = 0; j < 8; ++j) {
        const float4 wv = *(const float4*)(wtk + (og * 8 + j) * 128 + c4);
        acc[j][0] += wv.x * s0.x + wv.y * s1.x + wv.z * s2.x + wv.w * s3.x;
        acc[j][1] += wv.x * s0.y + wv.y * s1.y + wv.z * s2.y + wv.w * s3.y;
        acc[j][2] += wv.x * s0.z + wv.y * s1.z + wv.z * s2.z + wv.w * s3.z;
        acc[j][3] += wv.x * s0.w + wv.y * s1.w + wv.z * s2.w + wv.w * s3.w;
      }
    }
  }
  // epilogue: residual add + store
  for (int j = 0; j < 8; ++j) {
    int o = og * 8 + j;
    for (int pp = 0; pp < 4; ++pp) {
      int p = po4 + pp;
      int yy = Y0 + (p >> 3), xx = X0 + (p & 7);
      size_t oi = (((size_t)b * CD + o) * HD + yy) * WD + xx;
      out[oi] = acc[j][pp] + x[oi];
    }
  }
}

extern "C" void kernel_launch(void* const* d_in, const int* in_sizes, int n_in,
                              void* d_out, int out_size, void* d_ws, size_t ws_size,
                              hipStream_t stream) {
  const float* x = (const float*)d_in[0];
  const float* g1 = (const float*)d_in[1];
  const float* b1 = (const float*)d_in[2];
  const float* g2 = (const float*)d_in[3];
  const float* b2 = (const float*)d_in[4];
  const float* w1 = (const float*)d_in[5];
  const float* bc1 = (const float*)d_in[6];
  const float* w_off = (const float*)d_in[7];
  const float* b_off = (const float*)d_in[8];
  const float* w_def = (const float*)d_in[9];
  float* out = (float*)d_out;
  float* ws = (float*)d_ws;

  float* wt = ws;                   // 9*128*128      = 147456
  float* st1 = wt + 147456;         // 512*2          = 1024
  float* st2 = st1 + 1024;          // 1024
  float* h1 = st2 + 1024;           // 4*128*9216     = 4718592
  float* hB = h1 + 4718592;         // 4718592
  float* omb = hB + 4718592;        // 4*27*9216      = 995328

  transpose_wdef_kernel<<<576, 256, 0, stream>>>(w_def, wt);
  stats_kernel<<<512, 256, 0, stream>>>(x, st1);
  norm_lrelu_kernel<<<18432, 256, 0, stream>>>(x, st1, g1, b1, h1);
  conv3x3_kernel<<<dim3(9, 32, 4), 256, 0, stream>>>(h1, w1, bc1, hB, 128, 128);
  stats_kernel<<<512, 256, 0, stream>>>(hB, st2);
  norm_lrelu_kernel<<<18432, 256, 0, stream>>>(hB, st2, g2, b2, hB);
  conv3x3_kernel<<<dim3(9, 7, 4), 256, 0, stream>>>(hB, w_off, b_off, omb, 128, 27);
  deform_kernel<<<dim3(144, 4), 256, 0, stream>>>(hB, omb, wt, x, out);
}

// Round 2
// 1044.758 us; speedup vs baseline: 1.3040x; 1.3040x over previous
//
#include <hip/hip_runtime.h>
#include <math.h>

#define HWN 9216   // 96*96
#define HD 96
#define WD 96
#define CD 128
#define BD 4

// ---------------- transpose w_def[o][c][k] -> wt[k][o][c] ----------------
__global__ __launch_bounds__(256) void transpose_wdef_kernel(
    const float* __restrict__ wd, float* __restrict__ wt) {
  int i = blockIdx.x * 256 + threadIdx.x;
  if (i >= 9 * 128 * 128) return;
  int c = i & 127;
  int o = (i >> 7) & 127;
  int k = i >> 14;
  wt[i] = wd[o * 1152 + c * 9 + k];
}

// ---------------- per-(b,c) instance norm stats ----------------
__global__ __launch_bounds__(256) void stats_kernel(
    const float* __restrict__ src, float* __restrict__ stats) {
  int bc = blockIdx.x;  // b*C + c
  const float* p = src + (size_t)bc * HWN;
  float s = 0.f, s2 = 0.f;
  for (int i = threadIdx.x; i < HWN; i += 256) {
    float v = p[i];
    s += v;
    s2 += v * v;
  }
  for (int off = 32; off > 0; off >>= 1) {
    s += __shfl_down(s, off, 64);
    s2 += __shfl_down(s2, off, 64);
  }
  __shared__ float as[4], as2[4];
  int wid = threadIdx.x >> 6, lid = threadIdx.x & 63;
  if (lid == 0) { as[wid] = s; as2[wid] = s2; }
  __syncthreads();
  if (threadIdx.x == 0) {
    float S = 0.f, S2 = 0.f;
    for (int w = 0; w < 4; ++w) { S += as[w]; S2 += as2[w]; }
    float mu = S / (float)HWN;
    float var = S2 / (float)HWN - mu * mu;
    stats[bc * 2] = mu;
    stats[bc * 2 + 1] = rsqrtf(var + 1e-5f);
  }
}

// ---------------- normalize + LeakyReLU ----------------
__global__ __launch_bounds__(256) void norm_lrelu_kernel(
    const float* __restrict__ src, const float* __restrict__ stats,
    const float* __restrict__ gamma, const float* __restrict__ beta,
    float* __restrict__ dst) {
  int idx = blockIdx.x * 256 + threadIdx.x;  // total = 4*128*9216, exact grid
  int bc = idx / HWN;
  int c = bc & 127;
  float mu = stats[bc * 2], rs = stats[bc * 2 + 1];
  float v = (src[idx] - mu) * rs * gamma[c] + beta[c];
  dst[idx] = v >= 0.f ? v : 0.2f * v;
}

// ---------------- transpose hB [b][c][y][x] -> ht [b][y][x][c] ----------------
__global__ __launch_bounds__(256) void transpose_h_kernel(
    const float* __restrict__ src, float* __restrict__ dst) {
  __shared__ float tl[128][97];
  int b = blockIdx.y;
  int y = blockIdx.x;
  int t = threadIdx.x;
  const float* sb = src + (size_t)b * 128 * HWN + (size_t)y * WD;
  for (int i = t; i < 128 * 96; i += 256) {
    int c = i / 96, xx = i - c * 96;
    tl[c][xx] = sb[(size_t)c * HWN + xx];
  }
  __syncthreads();
  float* db = dst + ((size_t)b * HD + y) * WD * 128;
  for (int i = t; i < 96 * 128; i += 256) {
    int xx = i >> 7, c = i & 127;
    db[i] = tl[c][xx];
  }
}

// ---------------- direct 3x3 conv, pad=1 ----------------
__global__ __launch_bounds__(256) void conv3x3_kernel(
    const float* __restrict__ in, const float* __restrict__ w,
    const float* __restrict__ bias, float* __restrict__ out,
    int CI, int CO) {
  __shared__ float tile[34 * 34];
  __shared__ float wl[36];
  const int tgrid = 3;  // 96/32
  int tid = blockIdx.x;
  int ty0 = (tid / tgrid) * 32, tx0 = (tid % tgrid) * 32;
  int cog = blockIdx.y * 4;
  int b = blockIdx.z;
  int t = threadIdx.x;
  int lx = t & 15, ly = t >> 4;
  float acc[4][2][2] = {};
  const float* inb = in + (size_t)b * CI * HWN;
  for (int ci = 0; ci < CI; ++ci) {
    __syncthreads();
    const float* inc = inb + ci * HWN;
    for (int i = t; i < 34 * 34; i += 256) {
      int r = i / 34, cc = i % 34;
      int gy = ty0 - 1 + r, gx = tx0 - 1 + cc;
      float v = 0.f;
      if ((unsigned)gy < 96u && (unsigned)gx < 96u) v = inc[gy * WD + gx];
      tile[i] = v;
    }
    if (t < 36) {
      int j = t / 9, kk = t % 9;
      int co = cog + j;
      wl[t] = (co < CO) ? w[(size_t)co * CI * 9 + ci * 9 + kk] : 0.f;
    }
    __syncthreads();
    int Y = 2 * ly, X = 2 * lx;
    float inr[4][4];
#pragma unroll
    for (int r = 0; r < 4; ++r)
#pragma unroll
      for (int cc = 0; cc < 4; ++cc) inr[r][cc] = tile[(Y + r) * 34 + X + cc];
#pragma unroll
    for (int j = 0; j < 4; ++j) {
#pragma unroll
      for (int a = 0; a < 3; ++a)
#pragma unroll
        for (int bb = 0; bb < 3; ++bb) {
          float wv = wl[j * 9 + a * 3 + bb];
          acc[j][0][0] += inr[a][bb] * wv;
          acc[j][0][1] += inr[a][bb + 1] * wv;
          acc[j][1][0] += inr[a + 1][bb] * wv;
          acc[j][1][1] += inr[a + 1][bb + 1] * wv;
        }
    }
  }
  for (int j = 0; j < 4; ++j) {
    int co = cog + j;
    if (co >= CO) break;
    float bv = bias[co];
    for (int r = 0; r < 2; ++r)
      for (int cc = 0; cc < 2; ++cc) {
        int gy = ty0 + 2 * ly + r, gx = tx0 + 2 * lx + cc;
        out[(((size_t)b * CO + co) * HD + gy) * WD + gx] = acc[j][r][cc] + bv;
      }
  }
}

// ---------------- deformable conv + residual (channel-minor gather) ----------------
// grid: (144 tiles of 8x8, B); block 256
// ht: [b][y][x][c] channel-minor
__global__ __launch_bounds__(256) void deform_kernel(
    const float* __restrict__ ht, const float* __restrict__ om,
    const float* __restrict__ wt, const float* __restrict__ x,
    float* __restrict__ out) {
  __shared__ float Sk[64][128];   // [p][c], float4-units XOR-swizzled by (p&7)
  __shared__ int offs[64][4];     // float-offset (pix*128) per corner
  __shared__ float wgt[64][4];
  int b = blockIdx.y;
  int tileid = blockIdx.x;
  int Y0 = (tileid / 12) * 8, X0 = (tileid % 12) * 8;
  int t = threadIdx.x;
  const float* omb = om + (size_t)b * 27 * HWN;
  const float* htb = ht + (size_t)b * HWN * 128;

  int u = t & 31;    // channel float4-unit for gather
  int pg = t >> 5;   // 0..7
  int po = t & 15, og = t >> 4;  // GEMM mapping: o = og*8+j, p = po+16*i
  int sw = po & 7;               // (po+16*i)&7 == po&7
  float acc[8][4] = {};

  for (int k = 0; k < 9; ++k) {
    // phase 1: bilinear params for this k
    if (t < 64) {
      int p = t;
      int yy = Y0 + (p >> 3), xx = X0 + (p & 7);
      int pix = yy * WD + xx;
      float dy = omb[(2 * k) * HWN + pix];
      float dx = omb[(2 * k + 1) * HWN + pix];
      float mv = omb[(18 + k) * HWN + pix];
      float mask = 1.0f / (1.0f + expf(-mv));
      float py = dy + (float)(yy - 1 + (k / 3));
      float px = dx + (float)(xx - 1 + (k % 3));
      float fy = floorf(py), fx = floorf(px);
      float lyf = py - fy, lxf = px - fx;
      int y0 = (int)fy, x0 = (int)fx;
      int y1 = y0 + 1, x1 = x0 + 1;
      bool vy0 = (y0 >= 0) && (y0 < HD);
      bool vy1 = (y1 >= 0) && (y1 < HD);
      bool vx0 = (x0 >= 0) && (x0 < WD);
      bool vx1 = (x1 >= 0) && (x1 < WD);
      int y0c = min(max(y0, 0), HD - 1), y1c = min(max(y1, 0), HD - 1);
      int x0c = min(max(x0, 0), WD - 1), x1c = min(max(x1, 0), WD - 1);
      offs[p][0] = (y0c * WD + x0c) * 128;
      offs[p][1] = (y0c * WD + x1c) * 128;
      offs[p][2] = (y1c * WD + x0c) * 128;
      offs[p][3] = (y1c * WD + x1c) * 128;
      wgt[p][0] = (1.f - lyf) * (1.f - lxf) * ((vy0 && vx0) ? mask : 0.f);
      wgt[p][1] = (1.f - lyf) * lxf * ((vy0 && vx1) ? mask : 0.f);
      wgt[p][2] = lyf * (1.f - lxf) * ((vy1 && vx0) ? mask : 0.f);
      wgt[p][3] = lyf * lxf * ((vy1 && vx1) ? mask : 0.f);
    }
    __syncthreads();
    // phase 2: coalesced channel-vector gather. each 32-lane group: one p,
    // 4 corner reads of 512B contiguous.
#pragma unroll
    for (int j = 0; j < 8; ++j) {
      int p = pg * 8 + j;
      int c4 = u * 4;
      const float4 v0 = *(const float4*)(htb + offs[p][0] + c4);
      const float4 v1 = *(const float4*)(htb + offs[p][1] + c4);
      const float4 v2 = *(const float4*)(htb + offs[p][2] + c4);
      const float4 v3 = *(const float4*)(htb + offs[p][3] + c4);
      float w0 = wgt[p][0], w1 = wgt[p][1], w2 = wgt[p][2], w3 = wgt[p][3];
      float4 s;
      s.x = w0 * v0.x + w1 * v1.x + w2 * v2.x + w3 * v3.x;
      s.y = w0 * v0.y + w1 * v1.y + w2 * v2.y + w3 * v3.y;
      s.z = w0 * v0.z + w1 * v1.z + w2 * v2.z + w3 * v3.z;
      s.w = w0 * v0.w + w1 * v1.w + w2 * v2.w + w3 * v3.w;
      *(float4*)&Sk[p][(u ^ (p & 7)) * 4] = s;
    }
    __syncthreads();
    // phase 3: GEMM acc[o][p] += wt[k][o][c] * Sk[p][c]
    const float* wtk = wt + (size_t)k * 16384;
#pragma unroll 8
    for (int uu = 0; uu < 32; ++uu) {
      int su = (uu ^ sw) * 4;
      float4 s0 = *(const float4*)&Sk[po][su];
      float4 s1 = *(const float4*)&Sk[po + 16][su];
      float4 s2 = *(const float4*)&Sk[po + 32][su];
      float4 s3 = *(const float4*)&Sk[po + 48][su];
#pragma unroll
      for (int j = 0; j < 8; ++j) {
        const float4 wv = *(const float4*)(wtk + (og * 8 + j) * 128 + uu * 4);
        acc[j][0] += wv.x * s0.x + wv.y * s0.y + wv.z * s0.z + wv.w * s0.w;
        acc[j][1] += wv.x * s1.x + wv.y * s1.y + wv.z * s1.z + wv.w * s1.w;
        acc[j][2] += wv.x * s2.x + wv.y * s2.y + wv.z * s2.z + wv.w * s2.w;
        acc[j][3] += wv.x * s3.x + wv.y * s3.y + wv.z * s3.z + wv.w * s3.w;
      }
    }
  }
  // epilogue: residual add + store
  for (int j = 0; j < 8; ++j) {
    int o = og * 8 + j;
    for (int i = 0; i < 4; ++i) {
      int p = po + 16 * i;
      int yy = Y0 + (p >> 3), xx = X0 + (p & 7);
      size_t oi = (((size_t)b * CD + o) * HD + yy) * WD + xx;
      out[oi] = acc[j][i] + x[oi];
    }
  }
}

extern "C" void kernel_launch(void* const* d_in, const int* in_sizes, int n_in,
                              void* d_out, int out_size, void* d_ws, size_t ws_size,
                              hipStream_t stream) {
  const float* x = (const float*)d_in[0];
  const float* g1 = (const float*)d_in[1];
  const float* b1 = (const float*)d_in[2];
  const float* g2 = (const float*)d_in[3];
  const float* b2 = (const float*)d_in[4];
  const float* w1 = (const float*)d_in[5];
  const float* bc1 = (const float*)d_in[6];
  const float* w_off = (const float*)d_in[7];
  const float* b_off = (const float*)d_in[8];
  const float* w_def = (const float*)d_in[9];
  float* out = (float*)d_out;
  float* ws = (float*)d_ws;

  float* wt = ws;                   // 9*128*128      = 147456
  float* st1 = wt + 147456;         // 512*2          = 1024
  float* st2 = st1 + 1024;          // 1024
  float* h1 = st2 + 1024;           // 4*128*9216     = 4718592 (reused as ht)
  float* hB = h1 + 4718592;         // 4718592
  float* omb = hB + 4718592;        // 4*27*9216      = 995328
  float* ht = h1;                   // h1 is dead after conv1 -> reuse

  transpose_wdef_kernel<<<576, 256, 0, stream>>>(w_def, wt);
  stats_kernel<<<512, 256, 0, stream>>>(x, st1);
  norm_lrelu_kernel<<<18432, 256, 0, stream>>>(x, st1, g1, b1, h1);
  conv3x3_kernel<<<dim3(9, 32, 4), 256, 0, stream>>>(h1, w1, bc1, hB, 128, 128);
  stats_kernel<<<512, 256, 0, stream>>>(hB, st2);
  norm_lrelu_kernel<<<18432, 256, 0, stream>>>(hB, st2, g2, b2, hB);
  conv3x3_kernel<<<dim3(9, 7, 4), 256, 0, stream>>>(hB, w_off, b_off, omb, 128, 27);
  transpose_h_kernel<<<dim3(96, 4), 256, 0, stream>>>(hB, ht);
  deform_kernel<<<dim3(144, 4), 256, 0, stream>>>(ht, omb, wt, x, out);
}

// Round 3
// 162.873 us; speedup vs baseline: 8.3645x; 6.4145x over previous
//
#include <hip/hip_runtime.h>
#include <math.h>

#define HWN 9216   // 96*96
#define HD 96
#define WD 96

typedef short s8v __attribute__((ext_vector_type(8)));
typedef float f4v __attribute__((ext_vector_type(4)));

__device__ __forceinline__ unsigned f2b(float f) {
  unsigned u = __builtin_bit_cast(unsigned, f);
  return (u + 0x7fffu + ((u >> 16) & 1u)) >> 16;  // RNE to bf16 (low 16 bits)
}
__device__ __forceinline__ float b2f_lo(unsigned u) {
  return __builtin_bit_cast(float, u << 16);
}
__device__ __forceinline__ float b2f_hi(unsigned u) {
  return __builtin_bit_cast(float, u & 0xffff0000u);
}
__device__ __forceinline__ f4v mfma16(s8v a, s8v b, f4v c) {
  return __builtin_amdgcn_mfma_f32_16x16x32_bf16(a, b, c, 0, 0, 0);
}

// ---------------- pack conv weights [CO][128][9] -> [9][COT][4][64][8] bf16 ----------------
__global__ __launch_bounds__(256) void pack_conv_kernel(
    const float* __restrict__ w, ushort* __restrict__ dst, int CO_real, int COT) {
  int i = blockIdx.x * 256 + threadIdx.x;
  int total = 9 * COT * 4 * 64;
  if (i >= total) return;
  int lane = i & 63;
  int j = i >> 6;
  int ks = j & 3; j >>= 2;
  int cot = j % COT;
  int kk = j / COT;
  int co = cot * 16 + (lane & 15);
  int c0 = ks * 32 + (lane >> 4) * 8;
  ushort fr[8];
#pragma unroll
  for (int e = 0; e < 8; ++e) {
    float v = 0.f;
    if (co < CO_real) v = w[(size_t)(co * 128 + c0 + e) * 9 + kk];
    fr[e] = (ushort)f2b(v);
  }
  uint4 o4;
  o4.x = (unsigned)fr[0] | ((unsigned)fr[1] << 16);
  o4.y = (unsigned)fr[2] | ((unsigned)fr[3] << 16);
  o4.z = (unsigned)fr[4] | ((unsigned)fr[5] << 16);
  o4.w = (unsigned)fr[6] | ((unsigned)fr[7] << 16);
  *(uint4*)(dst + (size_t)i * 8) = o4;
}

// ---------------- per-(b,c) instance norm stats (NCHW fp32 input) ----------------
__global__ __launch_bounds__(256) void stats_kernel(
    const float* __restrict__ src, float* __restrict__ stats) {
  int bc = blockIdx.x;
  const float* p = src + (size_t)bc * HWN;
  float s = 0.f, s2 = 0.f;
  for (int i = threadIdx.x; i < HWN; i += 256) {
    float v = p[i];
    s += v;
    s2 += v * v;
  }
  for (int off = 32; off > 0; off >>= 1) {
    s += __shfl_down(s, off, 64);
    s2 += __shfl_down(s2, off, 64);
  }
  __shared__ float as[4], as2[4];
  int wid = threadIdx.x >> 6, lid = threadIdx.x & 63;
  if (lid == 0) { as[wid] = s; as2[wid] = s2; }
  __syncthreads();
  if (threadIdx.x == 0) {
    float S = 0.f, S2 = 0.f;
    for (int w = 0; w < 4; ++w) { S += as[w]; S2 += as2[w]; }
    float mu = S / (float)HWN;
    float var = S2 / (float)HWN - mu * mu;
    stats[bc * 2] = mu;
    stats[bc * 2 + 1] = rsqrtf(var + 1e-5f);
  }
}

// ---------------- norm + lrelu + transpose to channel-minor bf16 ----------------
// src NCHW fp32 -> dst [b][y][x][c] bf16 (as uint pairs)
__global__ __launch_bounds__(256) void nt_kernel(
    const float* __restrict__ src, const float* __restrict__ stats,
    const float* __restrict__ gamma, const float* __restrict__ beta,
    unsigned* __restrict__ dst) {
  __shared__ float tl[128][97];
  __shared__ float sa[128], sb[128];
  int b = blockIdx.y, y = blockIdx.x, t = threadIdx.x;
  if (t < 128) {
    float mu = stats[(b * 128 + t) * 2], rs = stats[(b * 128 + t) * 2 + 1];
    float a = rs * gamma[t];
    sa[t] = a;
    sb[t] = beta[t] - mu * a;
  }
  __syncthreads();
  const float* sbase = src + (size_t)b * 128 * HWN + y * WD;
  for (int i = t; i < 12288; i += 256) {
    int c = i / 96, xx = i - c * 96;
    float v = sbase[(size_t)c * HWN + xx] * sa[c] + sb[c];
    tl[c][xx] = v >= 0.f ? v : 0.2f * v;
  }
  __syncthreads();
  unsigned* dbase = dst + (size_t)(b * 96 + y) * 96 * 64;
  for (int i = t; i < 6144; i += 256) {
    int xx = i >> 6, c2 = i & 63;
    unsigned lo = f2b(tl[2 * c2][xx]);
    unsigned hi = f2b(tl[2 * c2 + 1][xx]);
    dbase[xx * 64 + c2] = lo | (hi << 16);
  }
}

// ---------------- MFMA 3x3 conv. MODE 0: CO=128 (conv1). MODE 1: CO=27 pad 32 (offset) ----
// inp: [b][y][x][c] bf16; wp packed [9][COT][4][64][8]; out NCHW fp32 (+bias)
template <int MODE>
__global__ __launch_bounds__(256) void conv_mfma(
    const ushort* __restrict__ inp, const ushort* __restrict__ wp,
    const float* __restrict__ bias, float* __restrict__ out) {
  constexpr int COT = MODE ? 2 : 8;
  constexpr int NPT = MODE ? 1 : 4;
  __shared__ ushort halo[100 * 128];  // chunk-swizzled by (row&7)
  int b = blockIdx.y;
  int tile = blockIdx.x;
  int Y0 = (tile / 12) * 8, X0 = (tile % 12) * 8;
  int t = threadIdx.x;
  int lane = t & 63, w = t >> 6;
  // stage 10x10x128 halo
  const ushort* ib = inp + (size_t)b * HWN * 128;
  for (int i = t; i < 400; i += 256) {
    int r = i >> 2, q = i & 3;
    int gy = Y0 - 1 + r / 10, gx = X0 - 1 + r % 10;
    bool inb = ((unsigned)gy < 96u) && ((unsigned)gx < 96u);
    const uint4* gp4 = (const uint4*)(ib + (size_t)(gy * 96 + gx) * 128 + q * 32);
#pragma unroll
    for (int cc = 0; cc < 4; ++cc) {
      uint4 v = inb ? gp4[cc] : make_uint4(0, 0, 0, 0);
      int ch = (q * 4 + cc) ^ (r & 7);
      *(uint4*)&halo[r * 128 + ch * 8] = v;
    }
  }
  __syncthreads();

  int po = lane & 15, kg = lane >> 4;
  int co_base = MODE ? 0 : w * 32;
  int p_base = MODE ? w * 16 : 0;
  f4v acc[2][NPT];
#pragma unroll
  for (int a = 0; a < 2; ++a)
#pragma unroll
    for (int p = 0; p < NPT; ++p) acc[a][p] = (f4v)(0.f);

  for (int kk = 0; kk < 9; ++kk) {
    int ky = kk / 3, kx = kk % 3;
    const ushort* wk = wp + (size_t)kk * COT * 2048;
#pragma unroll
    for (int ks = 0; ks < 4; ++ks) {
      s8v a0 = *(const s8v*)(wk + ((co_base / 16 + 0) * 4 + ks) * 512 + lane * 8);
      s8v a1 = *(const s8v*)(wk + ((co_base / 16 + 1) * 4 + ks) * 512 + lane * 8);
      s8v bf[NPT];
#pragma unroll
      for (int pt = 0; pt < NPT; ++pt) {
        int p = p_base + pt * 16 + po;
        int r = ((p >> 3) + ky) * 10 + (p & 7) + kx;
        int ch = (ks * 4 + kg) ^ (r & 7);
        bf[pt] = *(const s8v*)&halo[r * 128 + ch * 8];
      }
#pragma unroll
      for (int pt = 0; pt < NPT; ++pt) {
        acc[0][pt] = mfma16(a0, bf[pt], acc[0][pt]);
        acc[1][pt] = mfma16(a1, bf[pt], acc[1][pt]);
      }
    }
  }
  const int CO = MODE ? 27 : 128;
#pragma unroll
  for (int at = 0; at < 2; ++at)
#pragma unroll
    for (int pt = 0; pt < NPT; ++pt)
#pragma unroll
      for (int reg = 0; reg < 4; ++reg) {
        int co = co_base + at * 16 + kg * 4 + reg;
        if (co >= CO) continue;
        int p = p_base + pt * 16 + po;
        int gp = (Y0 + (p >> 3)) * 96 + X0 + (p & 7);
        out[(size_t)(b * CO + co) * HWN + gp] = acc[at][pt][reg] + bias[co];
      }
}

// ---------------- deformable conv (MFMA) + residual ----------------
// h2n: [b][y][x][c] bf16; om NCHW fp32 (27 ch); wdp packed [9][8][4][64][8]; out NCHW fp32
__global__ __launch_bounds__(256) void deform_mfma(
    const ushort* __restrict__ h2n, const float* __restrict__ om,
    const ushort* __restrict__ wdp, const float* __restrict__ x,
    float* __restrict__ out) {
  __shared__ ushort S[64 * 128];  // [p][c] bf16, chunk-swizzled by (p&7)
  __shared__ int offs[9][64][4];
  __shared__ float wgt[9][64][4];
  int b = blockIdx.y, tile = blockIdx.x;
  int Y0 = (tile / 12) * 8, X0 = (tile % 12) * 8;
  int t = threadIdx.x;
  int lane = t & 63, w = t >> 6;
  const float* omb = om + (size_t)b * 27 * HWN;
  const ushort* hb = h2n + (size_t)b * HWN * 128;

  // phase 1: bilinear params for all 9 taps
  for (int i = t; i < 576; i += 256) {
    int k = i >> 6, p = i & 63;
    int yy = Y0 + (p >> 3), xx = X0 + (p & 7);
    int pix = yy * WD + xx;
    float dy = omb[(2 * k) * HWN + pix];
    float dx = omb[(2 * k + 1) * HWN + pix];
    float mv = omb[(18 + k) * HWN + pix];
    float mask = 1.0f / (1.0f + expf(-mv));
    float py = dy + (float)(yy - 1 + (k / 3));
    float px = dx + (float)(xx - 1 + (k % 3));
    float fy = floorf(py), fx = floorf(px);
    float lyf = py - fy, lxf = px - fx;
    int y0 = (int)fy, x0 = (int)fx;
    int y1 = y0 + 1, x1 = x0 + 1;
    bool vy0 = (y0 >= 0) && (y0 < HD);
    bool vy1 = (y1 >= 0) && (y1 < HD);
    bool vx0 = (x0 >= 0) && (x0 < WD);
    bool vx1 = (x1 >= 0) && (x1 < WD);
    int y0c = min(max(y0, 0), HD - 1), y1c = min(max(y1, 0), HD - 1);
    int x0c = min(max(x0, 0), WD - 1), x1c = min(max(x1, 0), WD - 1);
    offs[k][p][0] = (y0c * WD + x0c) * 128;
    offs[k][p][1] = (y0c * WD + x1c) * 128;
    offs[k][p][2] = (y1c * WD + x0c) * 128;
    offs[k][p][3] = (y1c * WD + x1c) * 128;
    wgt[k][p][0] = (1.f - lyf) * (1.f - lxf) * ((vy0 && vx0) ? mask : 0.f);
    wgt[k][p][1] = (1.f - lyf) * lxf * ((vy0 && vx1) ? mask : 0.f);
    wgt[k][p][2] = lyf * (1.f - lxf) * ((vy1 && vx0) ? mask : 0.f);
    wgt[k][p][3] = lyf * lxf * ((vy1 && vx1) ? mask : 0.f);
  }
  __syncthreads();

  int po = lane & 15, kg = lane >> 4;
  int sp = t & 63, sq = t >> 6;  // sampler: p, c-quarter
  f4v acc[2][4];
#pragma unroll
  for (int a = 0; a < 2; ++a)
#pragma unroll
    for (int p = 0; p < 4; ++p) acc[a][p] = (f4v)(0.f);

  for (int k = 0; k < 9; ++k) {
    if (k) __syncthreads();
    // phase 2: sample S[p][c] (mask folded), bf16, swizzled
    {
      float sv[32];
#pragma unroll
      for (int e = 0; e < 32; ++e) sv[e] = 0.f;
#pragma unroll
      for (int corner = 0; corner < 4; ++corner) {
        int off = offs[k][sp][corner];
        float wc = wgt[k][sp][corner];
        const uint4* gp4 = (const uint4*)(hb + off + sq * 32);
#pragma unroll
        for (int cc = 0; cc < 4; ++cc) {
          uint4 v = gp4[cc];
          unsigned ar[4] = {v.x, v.y, v.z, v.w};
#pragma unroll
          for (int e = 0; e < 4; ++e) {
            sv[cc * 8 + 2 * e] += wc * b2f_lo(ar[e]);
            sv[cc * 8 + 2 * e + 1] += wc * b2f_hi(ar[e]);
          }
        }
      }
#pragma unroll
      for (int cc = 0; cc < 4; ++cc) {
        uint4 o4;
        o4.x = f2b(sv[cc * 8 + 0]) | (f2b(sv[cc * 8 + 1]) << 16);
        o4.y = f2b(sv[cc * 8 + 2]) | (f2b(sv[cc * 8 + 3]) << 16);
        o4.z = f2b(sv[cc * 8 + 4]) | (f2b(sv[cc * 8 + 5]) << 16);
        o4.w = f2b(sv[cc * 8 + 6]) | (f2b(sv[cc * 8 + 7]) << 16);
        int ch = (sq * 4 + cc) ^ (sp & 7);
        *(uint4*)&S[sp * 128 + ch * 8] = o4;
      }
    }
    __syncthreads();
    // phase 3: MFMA
    const ushort* wk = wdp + (size_t)k * 16384;
#pragma unroll
    for (int ks = 0; ks < 4; ++ks) {
      s8v a0 = *(const s8v*)(wk + ((w * 2 + 0) * 4 + ks) * 512 + lane * 8);
      s8v a1 = *(const s8v*)(wk + ((w * 2 + 1) * 4 + ks) * 512 + lane * 8);
#pragma unroll
      for (int pt = 0; pt < 4; ++pt) {
        int p = pt * 16 + po;
        int ch = (ks * 4 + kg) ^ (p & 7);
        s8v bf = *(const s8v*)&S[p * 128 + ch * 8];
        acc[0][pt] = mfma16(a0, bf, acc[0][pt]);
        acc[1][pt] = mfma16(a1, bf, acc[1][pt]);
      }
    }
  }
  // epilogue: residual + store
#pragma unroll
  for (int at = 0; at < 2; ++at)
#pragma unroll
    for (int pt = 0; pt < 4; ++pt)
#pragma unroll
      for (int reg = 0; reg < 4; ++reg) {
        int co = w * 32 + at * 16 + kg * 4 + reg;
        int p = pt * 16 + po;
        int gp = (Y0 + (p >> 3)) * 96 + X0 + (p & 7);
        size_t oi = (size_t)(b * 128 + co) * HWN + gp;
        out[oi] = acc[at][pt][reg] + x[oi];
      }
}

extern "C" void kernel_launch(void* const* d_in, const int* in_sizes, int n_in,
                              void* d_out, int out_size, void* d_ws, size_t ws_size,
                              hipStream_t stream) {
  const float* x = (const float*)d_in[0];
  const float* g1 = (const float*)d_in[1];
  const float* b1 = (const float*)d_in[2];
  const float* g2 = (const float*)d_in[3];
  const float* b2 = (const float*)d_in[4];
  const float* w1 = (const float*)d_in[5];
  const float* bc1 = (const float*)d_in[6];
  const float* w_off = (const float*)d_in[7];
  const float* b_off = (const float*)d_in[8];
  const float* w_def = (const float*)d_in[9];
  float* out = (float*)d_out;
  float* ws = (float*)d_ws;

  // workspace layout (float units)
  ushort* w1p = (ushort*)ws;                  // 147456 bf16 = 73728 f
  ushort* wofp = (ushort*)(ws + 73728);       // 36864 bf16  = 18432 f
  ushort* wdp = (ushort*)(ws + 92160);        // 147456 bf16 = 73728 f
  float* st1 = ws + 165888;                   // 1024
  float* st2 = ws + 166912;                   // 1024
  ushort* hA = (ushort*)(ws + 167936);        // 4718592 bf16 = 2359296 f (h1n, later h2n)
  float* hB = ws + 2527232;                   // 4718592 f (NCHW fp32)
  float* om = ws + 7245824;                   // 995328 f
  // total 8241152 floats = 33.0 MB

  pack_conv_kernel<<<72, 256, 0, stream>>>(w1, w1p, 128, 8);
  pack_conv_kernel<<<18, 256, 0, stream>>>(w_off, wofp, 27, 2);
  pack_conv_kernel<<<72, 256, 0, stream>>>(w_def, wdp, 128, 8);
  stats_kernel<<<512, 256, 0, stream>>>(x, st1);
  nt_kernel<<<dim3(96, 4), 256, 0, stream>>>(x, st1, g1, b1, (unsigned*)hA);
  conv_mfma<0><<<dim3(144, 4), 256, 0, stream>>>(hA, w1p, bc1, hB);
  stats_kernel<<<512, 256, 0, stream>>>(hB, st2);
  nt_kernel<<<dim3(96, 4), 256, 0, stream>>>(hB, st2, g2, b2, (unsigned*)hA);
  conv_mfma<1><<<dim3(144, 4), 256, 0, stream>>>(hA, wofp, b_off, om);
  deform_mfma<<<dim3(144, 4), 256, 0, stream>>>(hA, om, wdp, x, out);
}

// Round 4
// 142.267 us; speedup vs baseline: 9.5760x; 1.1448x over previous
//
#include <hip/hip_runtime.h>
#include <math.h>

#define HWN 9216   // 96*96
#define HD 96
#define WD 96

typedef short s8v __attribute__((ext_vector_type(8)));
typedef float f4v __attribute__((ext_vector_type(4)));

__device__ __forceinline__ unsigned f2b(float f) {
  unsigned u = __builtin_bit_cast(unsigned, f);
  return (u + 0x7fffu + ((u >> 16) & 1u)) >> 16;  // RNE to bf16 (low 16 bits)
}
__device__ __forceinline__ float b2f_lo(unsigned u) {
  return __builtin_bit_cast(float, u << 16);
}
__device__ __forceinline__ float b2f_hi(unsigned u) {
  return __builtin_bit_cast(float, u & 0xffff0000u);
}
__device__ __forceinline__ f4v mfma16(s8v a, s8v b, f4v c) {
  return __builtin_amdgcn_mfma_f32_16x16x32_bf16(a, b, c, 0, 0, 0);
}

// ---------------- pack conv weights [CO][128][9] -> [9][COT][4][64][8] bf16 ----------------
__global__ __launch_bounds__(256) void pack_conv_kernel(
    const float* __restrict__ w, ushort* __restrict__ dst, int CO_real, int COT) {
  int i = blockIdx.x * 256 + threadIdx.x;
  int total = 9 * COT * 4 * 64;
  if (i >= total) return;
  int lane = i & 63;
  int j = i >> 6;
  int ks = j & 3; j >>= 2;
  int cot = j % COT;
  int kk = j / COT;
  int co = cot * 16 + (lane & 15);
  int c0 = ks * 32 + (lane >> 4) * 8;
  ushort fr[8];
#pragma unroll
  for (int e = 0; e < 8; ++e) {
    float v = 0.f;
    if (co < CO_real) v = w[(size_t)(co * 128 + c0 + e) * 9 + kk];
    fr[e] = (ushort)f2b(v);
  }
  uint4 o4;
  o4.x = (unsigned)fr[0] | ((unsigned)fr[1] << 16);
  o4.y = (unsigned)fr[2] | ((unsigned)fr[3] << 16);
  o4.z = (unsigned)fr[4] | ((unsigned)fr[5] << 16);
  o4.w = (unsigned)fr[6] | ((unsigned)fr[7] << 16);
  *(uint4*)(dst + (size_t)i * 8) = o4;
}

// ---------------- per-(b,c) instance norm stats (NCHW fp32 input) ----------------
__global__ __launch_bounds__(256) void stats_kernel(
    const float* __restrict__ src, float* __restrict__ stats) {
  int bc = blockIdx.x;
  const float* p = src + (size_t)bc * HWN;
  float s = 0.f, s2 = 0.f;
  for (int i = threadIdx.x; i < HWN; i += 256) {
    float v = p[i];
    s += v;
    s2 += v * v;
  }
  for (int off = 32; off > 0; off >>= 1) {
    s += __shfl_down(s, off, 64);
    s2 += __shfl_down(s2, off, 64);
  }
  __shared__ float as[4], as2[4];
  int wid = threadIdx.x >> 6, lid = threadIdx.x & 63;
  if (lid == 0) { as[wid] = s; as2[wid] = s2; }
  __syncthreads();
  if (threadIdx.x == 0) {
    float S = 0.f, S2 = 0.f;
    for (int w = 0; w < 4; ++w) { S += as[w]; S2 += as2[w]; }
    float mu = S / (float)HWN;
    float var = S2 / (float)HWN - mu * mu;
    stats[bc * 2] = mu;
    stats[bc * 2 + 1] = rsqrtf(var + 1e-5f);
  }
}

// ---------------- norm + lrelu + transpose to channel-minor bf16 ----------------
__global__ __launch_bounds__(256) void nt_kernel(
    const float* __restrict__ src, const float* __restrict__ stats,
    const float* __restrict__ gamma, const float* __restrict__ beta,
    unsigned* __restrict__ dst) {
  __shared__ float tl[128][97];
  __shared__ float sa[128], sb[128];
  int b = blockIdx.y, y = blockIdx.x, t = threadIdx.x;
  if (t < 128) {
    float mu = stats[(b * 128 + t) * 2], rs = stats[(b * 128 + t) * 2 + 1];
    float a = rs * gamma[t];
    sa[t] = a;
    sb[t] = beta[t] - mu * a;
  }
  __syncthreads();
  const float* sbase = src + (size_t)b * 128 * HWN + y * WD;
  for (int i = t; i < 12288; i += 256) {
    int c = i / 96, xx = i - c * 96;
    float v = sbase[(size_t)c * HWN + xx] * sa[c] + sb[c];
    tl[c][xx] = v >= 0.f ? v : 0.2f * v;
  }
  __syncthreads();
  unsigned* dbase = dst + (size_t)(b * 96 + y) * 96 * 64;
  for (int i = t; i < 6144; i += 256) {
    int xx = i >> 6, c2 = i & 63;
    unsigned lo = f2b(tl[2 * c2][xx]);
    unsigned hi = f2b(tl[2 * c2 + 1][xx]);
    dbase[xx * 64 + c2] = lo | (hi << 16);
  }
}

// ---------------- MFMA 3x3 conv. MODE 0: CO=128 (conv1). MODE 1: CO=27 pad 32 (offset) ----
template <int MODE>
__global__ __launch_bounds__(256) void conv_mfma(
    const ushort* __restrict__ inp, const ushort* __restrict__ wp,
    const float* __restrict__ bias, float* __restrict__ out) {
  constexpr int COT = MODE ? 2 : 8;
  constexpr int NPT = MODE ? 1 : 4;
  __shared__ ushort halo[100 * 128];  // chunk-swizzled by (row&7)
  int b = blockIdx.y;
  int tile = blockIdx.x;
  int Y0 = (tile / 12) * 8, X0 = (tile % 12) * 8;
  int t = threadIdx.x;
  int lane = t & 63, w = t >> 6;
  const ushort* ib = inp + (size_t)b * HWN * 128;
  for (int i = t; i < 400; i += 256) {
    int r = i >> 2, q = i & 3;
    int gy = Y0 - 1 + r / 10, gx = X0 - 1 + r % 10;
    bool inb = ((unsigned)gy < 96u) && ((unsigned)gx < 96u);
    const uint4* gp4 = (const uint4*)(ib + (size_t)(gy * 96 + gx) * 128 + q * 32);
#pragma unroll
    for (int cc = 0; cc < 4; ++cc) {
      uint4 v = inb ? gp4[cc] : make_uint4(0, 0, 0, 0);
      int ch = (q * 4 + cc) ^ (r & 7);
      *(uint4*)&halo[r * 128 + ch * 8] = v;
    }
  }
  __syncthreads();

  int po = lane & 15, kg = lane >> 4;
  int co_base = MODE ? 0 : w * 32;
  int p_base = MODE ? w * 16 : 0;
  f4v acc[2][NPT];
#pragma unroll
  for (int a = 0; a < 2; ++a)
#pragma unroll
    for (int p = 0; p < NPT; ++p) acc[a][p] = (f4v)(0.f);

  for (int kk = 0; kk < 9; ++kk) {
    int ky = kk / 3, kx = kk % 3;
    const ushort* wk = wp + (size_t)kk * COT * 2048;
#pragma unroll
    for (int ks = 0; ks < 4; ++ks) {
      s8v a0 = *(const s8v*)(wk + ((co_base / 16 + 0) * 4 + ks) * 512 + lane * 8);
      s8v a1 = *(const s8v*)(wk + ((co_base / 16 + 1) * 4 + ks) * 512 + lane * 8);
      s8v bf[NPT];
#pragma unroll
      for (int pt = 0; pt < NPT; ++pt) {
        int p = p_base + pt * 16 + po;
        int r = ((p >> 3) + ky) * 10 + (p & 7) + kx;
        int ch = (ks * 4 + kg) ^ (r & 7);
        bf[pt] = *(const s8v*)&halo[r * 128 + ch * 8];
      }
#pragma unroll
      for (int pt = 0; pt < NPT; ++pt) {
        acc[0][pt] = mfma16(a0, bf[pt], acc[0][pt]);
        acc[1][pt] = mfma16(a1, bf[pt], acc[1][pt]);
      }
    }
  }
  const int CO = MODE ? 27 : 128;
#pragma unroll
  for (int at = 0; at < 2; ++at)
#pragma unroll
    for (int pt = 0; pt < NPT; ++pt)
#pragma unroll
      for (int reg = 0; reg < 4; ++reg) {
        int co = co_base + at * 16 + kg * 4 + reg;
        if (co >= CO) continue;
        int p = p_base + pt * 16 + po;
        int gp = (Y0 + (p >> 3)) * 96 + X0 + (p & 7);
        out[(size_t)(b * CO + co) * HWN + gp] = acc[at][pt][reg] + bias[co];
      }
}

// ---------------- deformable conv (MFMA, pipelined coalesced gather) + residual ---------
// 8x4 tiles, 1152 blocks, XCD-chunked swizzle, double-buffered S, reg-prefetched gather
__global__ __launch_bounds__(256) void deform_mfma(
    const ushort* __restrict__ h2n, const float* __restrict__ om,
    const ushort* __restrict__ wdp, const float* __restrict__ x,
    float* __restrict__ out) {
  __shared__ __align__(16) ushort S[2][32 * 128];  // [buf][p][c], chunk ^ (p&7)
  __shared__ int offs[9][32][4];
  __shared__ float wgt[9][32][4];
  int bid = blockIdx.x;
  int swz = (bid & 7) * 144 + (bid >> 3);  // bijective: 1152 % 8 == 0
  int b = swz / 288;
  int tile = swz % 288;
  int Y0 = (tile / 12) * 4, X0 = (tile % 12) * 8;
  int t = threadIdx.x;
  int lane = t & 63, w = t >> 6;
  const float* omb = om + (size_t)b * 27 * HWN;
  const ushort* hb = h2n + (size_t)b * HWN * 128;

  // phase 1: bilinear params for all 9 taps x 32 pos
  for (int i = t; i < 288; i += 256) {
    int k = i >> 5, p = i & 31;
    int yy = Y0 + (p >> 3), xx = X0 + (p & 7);
    int pix = yy * WD + xx;
    float dy = omb[(2 * k) * HWN + pix];
    float dx = omb[(2 * k + 1) * HWN + pix];
    float mv = omb[(18 + k) * HWN + pix];
    float mask = 1.0f / (1.0f + expf(-mv));
    float py = dy + (float)(yy - 1 + (k / 3));
    float px = dx + (float)(xx - 1 + (k % 3));
    float fy = floorf(py), fx = floorf(px);
    float lyf = py - fy, lxf = px - fx;
    int y0 = (int)fy, x0 = (int)fx;
    int y1 = y0 + 1, x1 = x0 + 1;
    bool vy0 = (y0 >= 0) && (y0 < HD);
    bool vy1 = (y1 >= 0) && (y1 < HD);
    bool vx0 = (x0 >= 0) && (x0 < WD);
    bool vx1 = (x1 >= 0) && (x1 < WD);
    int y0c = min(max(y0, 0), HD - 1), y1c = min(max(y1, 0), HD - 1);
    int x0c = min(max(x0, 0), WD - 1), x1c = min(max(x1, 0), WD - 1);
    offs[k][p][0] = (y0c * WD + x0c) * 128;
    offs[k][p][1] = (y0c * WD + x1c) * 128;
    offs[k][p][2] = (y1c * WD + x0c) * 128;
    offs[k][p][3] = (y1c * WD + x1c) * 128;
    wgt[k][p][0] = (1.f - lyf) * (1.f - lxf) * ((vy0 && vx0) ? mask : 0.f);
    wgt[k][p][1] = (1.f - lyf) * lxf * ((vy0 && vx1) ? mask : 0.f);
    wgt[k][p][2] = lyf * (1.f - lxf) * ((vy1 && vx0) ? mask : 0.f);
    wgt[k][p][3] = lyf * lxf * ((vy1 && vx1) ? mask : 0.f);
  }
  __syncthreads();

  int cc = t & 15;   // 16B channel-chunk within a pixel (8 channels)
  int pp = t >> 4;   // base pos 0..15; thread handles p = pp, pp+16
  int po = lane & 15, kg = lane >> 4;
  f4v acc[2][2];
#pragma unroll
  for (int a = 0; a < 2; ++a)
#pragma unroll
    for (int p = 0; p < 2; ++p) acc[a][p] = (f4v)(0.f);

  uint4 G[2][4];
  // prefetch k=0 gather (coalesced: 16 lanes span one pixel's 256B)
#pragma unroll
  for (int i = 0; i < 2; ++i) {
    int p = pp + 16 * i;
#pragma unroll
    for (int c = 0; c < 4; ++c)
      G[i][c] = *(const uint4*)(hb + offs[0][p][c] + cc * 8);
  }

  for (int k = 0; k < 9; ++k) {
    // blend G -> S[k&1] (bf16, swizzled)
#pragma unroll
    for (int i = 0; i < 2; ++i) {
      int p = pp + 16 * i;
      float sv[8] = {0.f, 0.f, 0.f, 0.f, 0.f, 0.f, 0.f, 0.f};
#pragma unroll
      for (int c = 0; c < 4; ++c) {
        float wc = wgt[k][p][c];
        unsigned u0 = G[i][c].x, u1 = G[i][c].y, u2 = G[i][c].z, u3 = G[i][c].w;
        sv[0] += wc * b2f_lo(u0); sv[1] += wc * b2f_hi(u0);
        sv[2] += wc * b2f_lo(u1); sv[3] += wc * b2f_hi(u1);
        sv[4] += wc * b2f_lo(u2); sv[5] += wc * b2f_hi(u2);
        sv[6] += wc * b2f_lo(u3); sv[7] += wc * b2f_hi(u3);
      }
      uint4 o4;
      o4.x = f2b(sv[0]) | (f2b(sv[1]) << 16);
      o4.y = f2b(sv[2]) | (f2b(sv[3]) << 16);
      o4.z = f2b(sv[4]) | (f2b(sv[5]) << 16);
      o4.w = f2b(sv[6]) | (f2b(sv[7]) << 16);
      int ch = cc ^ (p & 7);
      *(uint4*)&S[k & 1][p * 128 + ch * 8] = o4;
    }
    // prefetch gather for k+1 (stays in flight across the barrier: no vmcnt drain)
    if (k < 8) {
#pragma unroll
      for (int i = 0; i < 2; ++i) {
        int p = pp + 16 * i;
#pragma unroll
        for (int c = 0; c < 4; ++c)
          G[i][c] = *(const uint4*)(hb + offs[k + 1][p][c] + cc * 8);
      }
    }
    asm volatile("s_waitcnt lgkmcnt(0)" ::: "memory");
    __builtin_amdgcn_s_barrier();
    // MFMA phase on S[k&1]
    const ushort* wk = wdp + (size_t)k * 16384;
    const ushort* Sb = S[k & 1];
#pragma unroll
    for (int ks = 0; ks < 4; ++ks) {
      s8v a0 = *(const s8v*)(wk + ((w * 2 + 0) * 4 + ks) * 512 + lane * 8);
      s8v a1 = *(const s8v*)(wk + ((w * 2 + 1) * 4 + ks) * 512 + lane * 8);
#pragma unroll
      for (int pt = 0; pt < 2; ++pt) {
        int p = pt * 16 + po;
        int ch = (ks * 4 + kg) ^ (p & 7);
        s8v bf = *(const s8v*)&Sb[p * 128 + ch * 8];
        acc[0][pt] = mfma16(a0, bf, acc[0][pt]);
        acc[1][pt] = mfma16(a1, bf, acc[1][pt]);
      }
    }
  }
  // epilogue: residual + store
#pragma unroll
  for (int at = 0; at < 2; ++at)
#pragma unroll
    for (int pt = 0; pt < 2; ++pt)
#pragma unroll
      for (int reg = 0; reg < 4; ++reg) {
        int co = w * 32 + at * 16 + kg * 4 + reg;
        int p = pt * 16 + po;
        int gp = (Y0 + (p >> 3)) * 96 + X0 + (p & 7);
        size_t oi = (size_t)(b * 128 + co) * HWN + gp;
        out[oi] = acc[at][pt][reg] + x[oi];
      }
}

extern "C" void kernel_launch(void* const* d_in, const int* in_sizes, int n_in,
                              void* d_out, int out_size, void* d_ws, size_t ws_size,
                              hipStream_t stream) {
  const float* x = (const float*)d_in[0];
  const float* g1 = (const float*)d_in[1];
  const float* b1 = (const float*)d_in[2];
  const float* g2 = (const float*)d_in[3];
  const float* b2 = (const float*)d_in[4];
  const float* w1 = (const float*)d_in[5];
  const float* bc1 = (const float*)d_in[6];
  const float* w_off = (const float*)d_in[7];
  const float* b_off = (const float*)d_in[8];
  const float* w_def = (const float*)d_in[9];
  float* out = (float*)d_out;
  float* ws = (float*)d_ws;

  // workspace layout (float units)
  ushort* w1p = (ushort*)ws;                  // 147456 bf16 = 73728 f
  ushort* wofp = (ushort*)(ws + 73728);       // 36864 bf16  = 18432 f
  ushort* wdp = (ushort*)(ws + 92160);        // 147456 bf16 = 73728 f
  float* st1 = ws + 165888;                   // 1024
  float* st2 = ws + 166912;                   // 1024
  ushort* hA = (ushort*)(ws + 167936);        // 4718592 bf16 = 2359296 f
  float* hB = ws + 2527232;                   // 4718592 f (NCHW fp32)
  float* om = ws + 7245824;                   // 995328 f

  pack_conv_kernel<<<72, 256, 0, stream>>>(w1, w1p, 128, 8);
  pack_conv_kernel<<<18, 256, 0, stream>>>(w_off, wofp, 27, 2);
  pack_conv_kernel<<<72, 256, 0, stream>>>(w_def, wdp, 128, 8);
  stats_kernel<<<512, 256, 0, stream>>>(x, st1);
  nt_kernel<<<dim3(96, 4), 256, 0, stream>>>(x, st1, g1, b1, (unsigned*)hA);
  conv_mfma<0><<<dim3(144, 4), 256, 0, stream>>>(hA, w1p, bc1, hB);
  stats_kernel<<<512, 256, 0, stream>>>(hB, st2);
  nt_kernel<<<dim3(96, 4), 256, 0, stream>>>(hB, st2, g2, b2, (unsigned*)hA);
  conv_mfma<1><<<dim3(144, 4), 256, 0, stream>>>(hA, wofp, b_off, om);
  deform_mfma<<<dim3(1152), 256, 0, stream>>>(hA, om, wdp, x, out);
}

// Round 5
// 123.559 us; speedup vs baseline: 11.0259x; 1.1514x over previous
//
#include <hip/hip_runtime.h>
#include <hip/hip_fp16.h>
#include <math.h>

#define HWN 9216   // 96*96
#define HD 96
#define WD 96

typedef _Float16 h8v __attribute__((ext_vector_type(8)));
typedef float f4v __attribute__((ext_vector_type(4)));

__device__ __forceinline__ ushort f2h(float f) {
  return __half_as_ushort(__float2half(f));
}
__device__ __forceinline__ __half2 u2h(unsigned u) {
  return __builtin_bit_cast(__half2, u);
}
__device__ __forceinline__ unsigned h2u(__half2 h) {
  return __builtin_bit_cast(unsigned, h);
}
__device__ __forceinline__ f4v mfma16(h8v a, h8v b, f4v c) {
  return __builtin_amdgcn_mfma_f32_16x16x32_f16(a, b, c, 0, 0, 0);
}

// ---------------- pack conv weights [CO][128][9] -> [9][COT][4][64][8] f16 ----------------
__global__ __launch_bounds__(256) void pack_conv_kernel(
    const float* __restrict__ w, ushort* __restrict__ dst, int CO_real, int COT) {
  int i = blockIdx.x * 256 + threadIdx.x;
  int total = 9 * COT * 4 * 64;
  if (i >= total) return;
  int lane = i & 63;
  int j = i >> 6;
  int ks = j & 3; j >>= 2;
  int cot = j % COT;
  int kk = j / COT;
  int co = cot * 16 + (lane & 15);
  int c0 = ks * 32 + (lane >> 4) * 8;
  ushort fr[8];
#pragma unroll
  for (int e = 0; e < 8; ++e) {
    float v = 0.f;
    if (co < CO_real) v = w[(size_t)(co * 128 + c0 + e) * 9 + kk];
    fr[e] = f2h(v);
  }
  uint4 o4;
  o4.x = (unsigned)fr[0] | ((unsigned)fr[1] << 16);
  o4.y = (unsigned)fr[2] | ((unsigned)fr[3] << 16);
  o4.z = (unsigned)fr[4] | ((unsigned)fr[5] << 16);
  o4.w = (unsigned)fr[6] | ((unsigned)fr[7] << 16);
  *(uint4*)(dst + (size_t)i * 8) = o4;
}

// ---------------- per-(b,c) instance norm stats (NCHW fp32 input) ----------------
__global__ __launch_bounds__(256) void stats_kernel(
    const float* __restrict__ src, float* __restrict__ stats) {
  int bc = blockIdx.x;
  const float* p = src + (size_t)bc * HWN;
  float s = 0.f, s2 = 0.f;
  for (int i = threadIdx.x; i < HWN; i += 256) {
    float v = p[i];
    s += v;
    s2 += v * v;
  }
  for (int off = 32; off > 0; off >>= 1) {
    s += __shfl_down(s, off, 64);
    s2 += __shfl_down(s2, off, 64);
  }
  __shared__ float as[4], as2[4];
  int wid = threadIdx.x >> 6, lid = threadIdx.x & 63;
  if (lid == 0) { as[wid] = s; as2[wid] = s2; }
  __syncthreads();
  if (threadIdx.x == 0) {
    float S = 0.f, S2 = 0.f;
    for (int w = 0; w < 4; ++w) { S += as[w]; S2 += as2[w]; }
    float mu = S / (float)HWN;
    float var = S2 / (float)HWN - mu * mu;
    stats[bc * 2] = mu;
    stats[bc * 2 + 1] = rsqrtf(var + 1e-5f);
  }
}

// ---------------- norm + lrelu + transpose to channel-minor f16 ----------------
__global__ __launch_bounds__(256) void nt_kernel(
    const float* __restrict__ src, const float* __restrict__ stats,
    const float* __restrict__ gamma, const float* __restrict__ beta,
    unsigned* __restrict__ dst) {
  __shared__ float tl[128][97];
  __shared__ float sa[128], sb[128];
  int b = blockIdx.y, y = blockIdx.x, t = threadIdx.x;
  if (t < 128) {
    float mu = stats[(b * 128 + t) * 2], rs = stats[(b * 128 + t) * 2 + 1];
    float a = rs * gamma[t];
    sa[t] = a;
    sb[t] = beta[t] - mu * a;
  }
  __syncthreads();
  const float* sbase = src + (size_t)b * 128 * HWN + y * WD;
  for (int i = t; i < 12288; i += 256) {
    int c = i / 96, xx = i - c * 96;
    float v = sbase[(size_t)c * HWN + xx] * sa[c] + sb[c];
    tl[c][xx] = v >= 0.f ? v : 0.2f * v;
  }
  __syncthreads();
  unsigned* dbase = dst + (size_t)(b * 96 + y) * 96 * 64;
  for (int i = t; i < 6144; i += 256) {
    int xx = i >> 6, c2 = i & 63;
    unsigned lo = f2h(tl[2 * c2][xx]);
    unsigned hi = f2h(tl[2 * c2 + 1][xx]);
    dbase[xx * 64 + c2] = lo | (hi << 16);
  }
}

// ---------------- conv1: MFMA 3x3, CO=128, 8 waves, channel-minor f16 out + stat partials -
__global__ __launch_bounds__(512) void conv1_mfma(
    const ushort* __restrict__ inp, const ushort* __restrict__ wp,
    const float* __restrict__ bias, ushort* __restrict__ outh,
    float* __restrict__ partS, float* __restrict__ partQ) {
  __shared__ ushort halo[100 * 128];  // chunk-swizzled by (row&7)
  int b = blockIdx.y;
  int tile = blockIdx.x;
  int Y0 = (tile / 12) * 8, X0 = (tile % 12) * 8;
  int t = threadIdx.x;
  int lane = t & 63, w = t >> 6;  // w 0..7 = co-tile
  const ushort* ib = inp + (size_t)b * HWN * 128;
  for (int i = t; i < 400; i += 512) {
    int r = i >> 2, q = i & 3;
    int gy = Y0 - 1 + r / 10, gx = X0 - 1 + r % 10;
    bool inb = ((unsigned)gy < 96u) && ((unsigned)gx < 96u);
    const uint4* gp4 = (const uint4*)(ib + (size_t)(gy * 96 + gx) * 128 + q * 32);
#pragma unroll
    for (int cc = 0; cc < 4; ++cc) {
      uint4 v = inb ? gp4[cc] : make_uint4(0, 0, 0, 0);
      int ch = (q * 4 + cc) ^ (r & 7);
      *(uint4*)&halo[r * 128 + ch * 8] = v;
    }
  }
  __syncthreads();

  int po = lane & 15, kg = lane >> 4;
  f4v acc[4];
#pragma unroll
  for (int p = 0; p < 4; ++p) acc[p] = (f4v)(0.f);

  for (int kk = 0; kk < 9; ++kk) {
    int ky = kk / 3, kx = kk % 3;
#pragma unroll
    for (int ks = 0; ks < 4; ++ks) {
      h8v a0 = *(const h8v*)(wp + (size_t)((kk * 8 + w) * 4 + ks) * 512 + lane * 8);
#pragma unroll
      for (int pt = 0; pt < 4; ++pt) {
        int p = pt * 16 + po;
        int r = ((p >> 3) + ky) * 10 + (p & 7) + kx;
        int ch = (ks * 4 + kg) ^ (r & 7);
        h8v bf = *(const h8v*)&halo[r * 128 + ch * 8];
        acc[pt] = mfma16(a0, bf, acc[pt]);
      }
    }
  }
  // epilogue: +bias, write channel-minor f16, accumulate stat partials
  int co0 = w * 16 + kg * 4;
  float bv[4];
#pragma unroll
  for (int r = 0; r < 4; ++r) bv[r] = bias[co0 + r];
  float s[4] = {0.f, 0.f, 0.f, 0.f}, q[4] = {0.f, 0.f, 0.f, 0.f};
#pragma unroll
  for (int pt = 0; pt < 4; ++pt) {
    int p = pt * 16 + po;
    int gp = (Y0 + (p >> 3)) * 96 + X0 + (p & 7);
    float v0 = acc[pt][0] + bv[0], v1 = acc[pt][1] + bv[1];
    float v2 = acc[pt][2] + bv[2], v3 = acc[pt][3] + bv[3];
    uint2 o;
    o.x = (unsigned)f2h(v0) | ((unsigned)f2h(v1) << 16);
    o.y = (unsigned)f2h(v2) | ((unsigned)f2h(v3) << 16);
    *(uint2*)&outh[((size_t)b * HWN + gp) * 128 + co0] = o;
    s[0] += v0; s[1] += v1; s[2] += v2; s[3] += v3;
    q[0] += v0 * v0; q[1] += v1 * v1; q[2] += v2 * v2; q[3] += v3 * v3;
  }
#pragma unroll
  for (int r = 0; r < 4; ++r)
#pragma unroll
    for (int m = 1; m < 16; m <<= 1) {
      s[r] += __shfl_xor(s[r], m, 16);
      q[r] += __shfl_xor(q[r], m, 16);
    }
  if (po == 0) {
#pragma unroll
    for (int r = 0; r < 4; ++r) {
      partS[((size_t)b * 144 + tile) * 128 + co0 + r] = s[r];
      partQ[((size_t)b * 144 + tile) * 128 + co0 + r] = q[r];
    }
  }
}

// ---------------- finalize IN2 stats: partials -> (sa, sb) ----------------
__global__ __launch_bounds__(256) void finalize_kernel(
    const float* __restrict__ partS, const float* __restrict__ partQ,
    const float* __restrict__ gamma, const float* __restrict__ beta,
    float* __restrict__ sa_, float* __restrict__ sb_) {
  int id = blockIdx.x * 256 + threadIdx.x;  // 512 total
  int b = id >> 7, c = id & 127;
  float S = 0.f, Q = 0.f;
  for (int tl = 0; tl < 144; ++tl) {
    S += partS[((size_t)b * 144 + tl) * 128 + c];
    Q += partQ[((size_t)b * 144 + tl) * 128 + c];
  }
  float mu = S / (float)HWN;
  float var = Q / (float)HWN - mu * mu;
  float rs = rsqrtf(var + 1e-5f);
  float a = rs * gamma[c];
  sa_[id] = a;
  sb_[id] = beta[c] - mu * a;
}

// ---------------- affine + lrelu (channel-minor f16 -> channel-minor f16) ----------------
__global__ __launch_bounds__(256) void affine_kernel(
    const ushort* __restrict__ src, const float* __restrict__ sa_,
    const float* __restrict__ sb_, ushort* __restrict__ dst) {
  __shared__ float sa[128], sb[128];
  int b = blockIdx.y, t = threadIdx.x;
  if (t < 128) { sa[t] = sa_[b * 128 + t]; sb[t] = sb_[b * 128 + t]; }
  __syncthreads();
  size_t base = ((size_t)b * HWN + blockIdx.x * 16) * 128 + t * 8;
  int c0 = (t & 15) * 8;
  uint4 v = *(const uint4*)&src[base];
  unsigned ar[4] = {v.x, v.y, v.z, v.w};
  uint4 o;
  unsigned orr[4];
#pragma unroll
  for (int j = 0; j < 4; ++j) {
    float2 f = __half22float2(u2h(ar[j]));
    int c = c0 + 2 * j;
    float x0 = f.x * sa[c] + sb[c];
    float x1 = f.y * sa[c + 1] + sb[c + 1];
    x0 = x0 >= 0.f ? x0 : 0.2f * x0;
    x1 = x1 >= 0.f ? x1 : 0.2f * x1;
    orr[j] = (unsigned)f2h(x0) | ((unsigned)f2h(x1) << 16);
  }
  o.x = orr[0]; o.y = orr[1]; o.z = orr[2]; o.w = orr[3];
  *(uint4*)&dst[base] = o;
}

// ---------------- offset conv: MFMA 3x3, CO=27 (pad 32), 4 waves, NCHW fp32 out ----------
__global__ __launch_bounds__(256) void convoff_mfma(
    const ushort* __restrict__ inp, const ushort* __restrict__ wp,
    const float* __restrict__ bias, float* __restrict__ out) {
  __shared__ ushort halo[100 * 128];
  int b = blockIdx.y;
  int tile = blockIdx.x;
  int Y0 = (tile / 12) * 8, X0 = (tile % 12) * 8;
  int t = threadIdx.x;
  int lane = t & 63, w = t >> 6;
  const ushort* ib = inp + (size_t)b * HWN * 128;
  for (int i = t; i < 400; i += 256) {
    int r = i >> 2, q = i & 3;
    int gy = Y0 - 1 + r / 10, gx = X0 - 1 + r % 10;
    bool inb = ((unsigned)gy < 96u) && ((unsigned)gx < 96u);
    const uint4* gp4 = (const uint4*)(ib + (size_t)(gy * 96 + gx) * 128 + q * 32);
#pragma unroll
    for (int cc = 0; cc < 4; ++cc) {
      uint4 v = inb ? gp4[cc] : make_uint4(0, 0, 0, 0);
      int ch = (q * 4 + cc) ^ (r & 7);
      *(uint4*)&halo[r * 128 + ch * 8] = v;
    }
  }
  __syncthreads();

  int po = lane & 15, kg = lane >> 4;
  int p_base = w * 16;
  f4v acc[2];
  acc[0] = (f4v)(0.f);
  acc[1] = (f4v)(0.f);

  for (int kk = 0; kk < 9; ++kk) {
    int ky = kk / 3, kx = kk % 3;
#pragma unroll
    for (int ks = 0; ks < 4; ++ks) {
      h8v a0 = *(const h8v*)(wp + (size_t)((kk * 2 + 0) * 4 + ks) * 512 + lane * 8);
      h8v a1 = *(const h8v*)(wp + (size_t)((kk * 2 + 1) * 4 + ks) * 512 + lane * 8);
      int p = p_base + po;
      int r = ((p >> 3) + ky) * 10 + (p & 7) + kx;
      int ch = (ks * 4 + kg) ^ (r & 7);
      h8v bf = *(const h8v*)&halo[r * 128 + ch * 8];
      acc[0] = mfma16(a0, bf, acc[0]);
      acc[1] = mfma16(a1, bf, acc[1]);
    }
  }
#pragma unroll
  for (int at = 0; at < 2; ++at)
#pragma unroll
    for (int reg = 0; reg < 4; ++reg) {
      int co = at * 16 + kg * 4 + reg;
      if (co >= 27) continue;
      int p = p_base + po;
      int gp = (Y0 + (p >> 3)) * 96 + X0 + (p & 7);
      out[(size_t)(b * 27 + co) * HWN + gp] = acc[at][reg] + bias[co];
    }
}

// ---------------- deformable conv (MFMA, f16 packed blend, 8 waves, 8x8 tiles) -----------
__global__ __launch_bounds__(512) void deform_mfma(
    const ushort* __restrict__ h2n, const float* __restrict__ om,
    const ushort* __restrict__ wdp, const float* __restrict__ x,
    float* __restrict__ out) {
  __shared__ __align__(16) ushort S[2][64 * 128];  // [buf][p][c], chunk ^ (p&7)
  __shared__ int offs[9][64][4];
  __shared__ float wgt[9][64][4];
  int bid = blockIdx.x;
  int swz = (bid & 7) * 72 + (bid >> 3);  // bijective: 576 % 8 == 0
  int b = swz / 144;
  int tile = swz % 144;
  int Y0 = (tile / 12) * 8, X0 = (tile % 12) * 8;
  int t = threadIdx.x;
  int lane = t & 63, w = t >> 6;
  const float* omb = om + (size_t)b * 27 * HWN;
  const ushort* hb = h2n + (size_t)b * HWN * 128;

  // phase 1: bilinear params for 9 taps x 64 pos
  for (int i = t; i < 576; i += 512) {
    int k = i >> 6, p = i & 63;
    int yy = Y0 + (p >> 3), xx = X0 + (p & 7);
    int pix = yy * WD + xx;
    float dy = omb[(2 * k) * HWN + pix];
    float dx = omb[(2 * k + 1) * HWN + pix];
    float mv = omb[(18 + k) * HWN + pix];
    float mask = 1.0f / (1.0f + expf(-mv));
    float py = dy + (float)(yy - 1 + (k / 3));
    float px = dx + (float)(xx - 1 + (k % 3));
    float fy = floorf(py), fx = floorf(px);
    float lyf = py - fy, lxf = px - fx;
    int y0 = (int)fy, x0 = (int)fx;
    int y1 = y0 + 1, x1 = x0 + 1;
    bool vy0 = (y0 >= 0) && (y0 < HD);
    bool vy1 = (y1 >= 0) && (y1 < HD);
    bool vx0 = (x0 >= 0) && (x0 < WD);
    bool vx1 = (x1 >= 0) && (x1 < WD);
    int y0c = min(max(y0, 0), HD - 1), y1c = min(max(y1, 0), HD - 1);
    int x0c = min(max(x0, 0), WD - 1), x1c = min(max(x1, 0), WD - 1);
    offs[k][p][0] = (y0c * WD + x0c) * 128;
    offs[k][p][1] = (y0c * WD + x1c) * 128;
    offs[k][p][2] = (y1c * WD + x0c) * 128;
    offs[k][p][3] = (y1c * WD + x1c) * 128;
    wgt[k][p][0] = (1.f - lyf) * (1.f - lxf) * ((vy0 && vx0) ? mask : 0.f);
    wgt[k][p][1] = (1.f - lyf) * lxf * ((vy0 && vx1) ? mask : 0.f);
    wgt[k][p][2] = lyf * (1.f - lxf) * ((vy1 && vx0) ? mask : 0.f);
    wgt[k][p][3] = lyf * lxf * ((vy1 && vx1) ? mask : 0.f);
  }
  __syncthreads();

  int cc = t & 15;   // 16B channel-chunk within a pixel
  int pp = t >> 4;   // 0..31; thread handles p = pp, pp+32
  int po = lane & 15, kg = lane >> 4;
  f4v acc[4];
#pragma unroll
  for (int p = 0; p < 4; ++p) acc[p] = (f4v)(0.f);

  uint4 G[2][4];
#pragma unroll
  for (int i = 0; i < 2; ++i) {
    int p = pp + 32 * i;
#pragma unroll
    for (int c = 0; c < 4; ++c)
      G[i][c] = *(const uint4*)(hb + offs[0][p][c] + cc * 8);
  }

  for (int k = 0; k < 9; ++k) {
    // blend G -> S[k&1] with packed f16 fma
#pragma unroll
    for (int i = 0; i < 2; ++i) {
      int p = pp + 32 * i;
      __half2 s0 = __float2half2_rn(0.f), s1 = s0, s2 = s0, s3 = s0;
#pragma unroll
      for (int c = 0; c < 4; ++c) {
        __half2 w2 = __float2half2_rn(wgt[k][p][c]);
        uint4 g = G[i][c];
        s0 = __hfma2(u2h(g.x), w2, s0);
        s1 = __hfma2(u2h(g.y), w2, s1);
        s2 = __hfma2(u2h(g.z), w2, s2);
        s3 = __hfma2(u2h(g.w), w2, s3);
      }
      uint4 o4;
      o4.x = h2u(s0); o4.y = h2u(s1); o4.z = h2u(s2); o4.w = h2u(s3);
      int ch = cc ^ (p & 7);
      *(uint4*)&S[k & 1][p * 128 + ch * 8] = o4;
    }
    // prefetch gather for k+1 (stays in flight across the barrier)
    if (k < 8) {
#pragma unroll
      for (int i = 0; i < 2; ++i) {
        int p = pp + 32 * i;
#pragma unroll
        for (int c = 0; c < 4; ++c)
          G[i][c] = *(const uint4*)(hb + offs[k + 1][p][c] + cc * 8);
      }
    }
    asm volatile("s_waitcnt lgkmcnt(0)" ::: "memory");
    __builtin_amdgcn_s_barrier();
    // MFMA phase on S[k&1]
    const ushort* wk = wdp + (size_t)k * 8 * 2048;
    const ushort* Sb = S[k & 1];
#pragma unroll
    for (int ks = 0; ks < 4; ++ks) {
      h8v a0 = *(const h8v*)(wk + (size_t)(w * 4 + ks) * 512 + lane * 8);
#pragma unroll
      for (int pt = 0; pt < 4; ++pt) {
        int p = pt * 16 + po;
        int ch = (ks * 4 + kg) ^ (p & 7);
        h8v bf = *(const h8v*)&Sb[p * 128 + ch * 8];
        acc[pt] = mfma16(a0, bf, acc[pt]);
      }
    }
  }
  // epilogue: residual + store
#pragma unroll
  for (int pt = 0; pt < 4; ++pt)
#pragma unroll
    for (int reg = 0; reg < 4; ++reg) {
      int co = w * 16 + kg * 4 + reg;
      int p = pt * 16 + po;
      int gp = (Y0 + (p >> 3)) * 96 + X0 + (p & 7);
      size_t oi = (size_t)(b * 128 + co) * HWN + gp;
      out[oi] = acc[pt][reg] + x[oi];
    }
}

extern "C" void kernel_launch(void* const* d_in, const int* in_sizes, int n_in,
                              void* d_out, int out_size, void* d_ws, size_t ws_size,
                              hipStream_t stream) {
  const float* x = (const float*)d_in[0];
  const float* g1 = (const float*)d_in[1];
  const float* b1 = (const float*)d_in[2];
  const float* g2 = (const float*)d_in[3];
  const float* b2 = (const float*)d_in[4];
  const float* w1 = (const float*)d_in[5];
  const float* bc1 = (const float*)d_in[6];
  const float* w_off = (const float*)d_in[7];
  const float* b_off = (const float*)d_in[8];
  const float* w_def = (const float*)d_in[9];
  float* out = (float*)d_out;
  float* ws = (float*)d_ws;

  // workspace layout (float units)
  ushort* w1p = (ushort*)ws;                   // [9][8][4][64][8] f16 = 73728 f
  ushort* wofp = (ushort*)(ws + 73728);        // [9][2][4][64][8] f16 = 18432 f
  ushort* wdp = (ushort*)(ws + 92160);         // 73728 f
  float* st1 = ws + 165888;                    // 1024
  float* st2a = ws + 166912;                   // 512
  float* st2b = ws + 167424;                   // 512
  float* partS = ws + 167936;                  // 73728
  float* partQ = ws + 241664;                  // 73728
  ushort* hA = (ushort*)(ws + 315392);         // 4718592 f16 = 2359296 f (norm1 out, then norm2 out)
  ushort* hBh = (ushort*)(ws + 2674688);       // 2359296 f (conv1 out, channel-minor f16)
  float* om = ws + 5033984;                    // 995328 f

  pack_conv_kernel<<<72, 256, 0, stream>>>(w1, w1p, 128, 8);
  pack_conv_kernel<<<18, 256, 0, stream>>>(w_off, wofp, 27, 2);
  pack_conv_kernel<<<72, 256, 0, stream>>>(w_def, wdp, 128, 8);
  stats_kernel<<<512, 256, 0, stream>>>(x, st1);
  nt_kernel<<<dim3(96, 4), 256, 0, stream>>>(x, st1, g1, b1, (unsigned*)hA);
  conv1_mfma<<<dim3(144, 4), 512, 0, stream>>>(hA, w1p, bc1, hBh, partS, partQ);
  finalize_kernel<<<2, 256, 0, stream>>>(partS, partQ, g2, b2, st2a, st2b);
  affine_kernel<<<dim3(576, 4), 256, 0, stream>>>(hBh, st2a, st2b, hA);
  convoff_mfma<<<dim3(144, 4), 256, 0, stream>>>(hA, wofp, b_off, om);
  deform_mfma<<<dim3(576), 512, 0, stream>>>(hA, om, wdp, x, out);
}